// Round 2
// baseline (619.864 us; speedup 1.0000x reference)
//
#include <hip/hip_runtime.h>
#include <stdint.h>
#include <stddef.h>

// Causal GQA prefill attention, MI355X gfx950.
// Round 5: XOR-swizzled LDS tile image to kill staging-write bank conflicts.
// Round-4 counters: SQ_LDS_BANK_CONFLICT=3.12e7 (~224 cyc/tile/wave, > the
// tile's 160-cyc MFMA budget). Cause: V writes hit a 1024B lane stride (16-way
// conflict), K writes 8-way. Fix (T2): swizzle slot index by block index,
// identical function at write and read; read-side the term is quarter-wave
// uniform so read patterns stay <=2-way (free per m136).
//
// Verified math pipeline (rounds 0-4): S^T = K*Q^T via mfma_16x16x32_bf16;
// its C-layout (row=key=quad*4+r, col=q=l15) equals the A-operand layout of
// mfma_16x16x16bf16_1k, so softmaxed P feeds PV straight from registers.
//
// LDS tile image (32768 B per 64-key tile, double buffered = 64 KB):
//   K-part (16384 B): chunk c in 0..15, key r in 0..63:
//       elem [c*512 + (r>>4)*128 + ((r&15) ^ ((c>>1)&7))*8] = K[r][c*8..c*8+7]
//   V-part (16384 B): unit u in 0..15, d in 0..127:
//       elem [KPART + u*512 + (d ^ u)*4] = V[u*4 .. u*4+3][d]  (V^T, bf16x4)

#define S_LEN   2048
#define HQ      32
#define HKV     8
#define DH      128
#define QSTRIDE (HQ*DH)
#define KSTRIDE (HKV*DH)
// (1/sqrt(128)) * log2(e): softmax in exp2 space
#define SCALE_L2 0.12751139830213113f

#define KTILE      64
#define NTILES     (S_LEN/KTILE)          // 32
#define TILE_ELEMS 16384                  // bf16 elems per tile image (32 KB)
#define KPART      8192                   // elems in K-part

typedef __bf16 bf16;
typedef short        s16x4 __attribute__((ext_vector_type(4)));
typedef short        s16x8 __attribute__((ext_vector_type(8)));
typedef float        f32x4 __attribute__((ext_vector_type(4)));
typedef unsigned int u32x2 __attribute__((ext_vector_type(2)));
typedef unsigned int u32x4 __attribute__((ext_vector_type(4)));

__device__ __forceinline__ unsigned int pk2(float a, float b) {
  union { bf16 h[2]; unsigned int u; } x;
  x.h[0] = (bf16)a; x.h[1] = (bf16)b;    // fptrunc = RNE
  return x.u;
}

// swizzled elem offsets inside the tile image
__device__ __forceinline__ int koff(int chunk, int key) {
  return chunk*512 + (key >> 4)*128 + (((key & 15) ^ ((chunk >> 1) & 7)))*8;
}
__device__ __forceinline__ int voff(int unit, int d) {
  return KPART + unit*512 + (d ^ unit)*4;
}

__global__ __launch_bounds__(512, 4)
void attn_fwd(const float* __restrict__ qg, const float* __restrict__ kg,
              const float* __restrict__ vg, float* __restrict__ og) {
  __shared__ bf16 smem[2*TILE_ELEMS];    // 65,536 B, double-buffered

  const int tid   = threadIdx.x;
  const int lane  = tid & 63;
  const int wave  = tid >> 6;            // 8 waves/block
  const int l15   = lane & 15;
  const int quad  = lane >> 4;
  const int pairp = blockIdx.x;          // 0..7
  const int h     = blockIdx.y;          // 0..31
  const int b     = blockIdx.z;          // 0..1
  const int hkv   = h >> 2;

  // staging roles: 512 threads cover the 64x128 K tile and 64x128 V tile
  const int fk_key = tid >> 3, fk_cg = tid & 7;      // K: 2 chunks / thread
  const int fv_u   = tid & 15, fv_dq = tid >> 4;     // V: unit, d-quad
  float4 fkx[4], fvx[4];

  auto load_regs = [&](int t) {
    const float* kp = kg + (size_t)(b*S_LEN + t*KTILE + fk_key)*KSTRIDE
                         + hkv*DH + fk_cg*16;
#pragma unroll
    for (int i = 0; i < 4; ++i) fkx[i] = ((const float4*)kp)[i];
    const int d0 = fv_dq*4;
#pragma unroll
    for (int j = 0; j < 4; ++j)
      fvx[j] = *(const float4*)(vg + (size_t)(b*S_LEN + t*KTILE + fv_u*4 + j)*KSTRIDE
                                   + hkv*DH + d0);
  };
  auto store_tile = [&](int bi) {
    bf16* kb = smem + bi*TILE_ELEMS;
#pragma unroll
    for (int ii = 0; ii < 2; ++ii) {
      u32x4 w;
      w[0] = pk2(fkx[2*ii].x,   fkx[2*ii].y);   w[1] = pk2(fkx[2*ii].z,   fkx[2*ii].w);
      w[2] = pk2(fkx[2*ii+1].x, fkx[2*ii+1].y); w[3] = pk2(fkx[2*ii+1].z, fkx[2*ii+1].w);
      // same-key writer lanes have distinct chunk>>1 -> distinct slots: no conflict
      *(u32x4*)(kb + koff(fk_cg*2 + ii, fk_key)) = w;
    }
    const float* g0 = (const float*)&fvx[0];
    const float* g1 = (const float*)&fvx[1];
    const float* g2 = (const float*)&fvx[2];
    const float* g3 = (const float*)&fvx[3];
#pragma unroll
    for (int i = 0; i < 4; ++i) {
      u32x2 w;
      w[0] = pk2(g0[i], g1[i]);
      w[1] = pk2(g2[i], g3[i]);
      // same-d writer lanes (unit=0..15) -> 16 distinct 8B slots = 32 banks
      *(u32x2*)(kb + voff(fv_u, fv_dq*4 + i)) = w;
    }
  };

  f32x4 oacc[8];
  float m_run, l_run;
  u32x4 qf[4];

  const int qbs[2] = { pairp, 15 - pairp };     // balanced: 34 steps total
  load_regs(0);

  int gs = 0;                                   // flat step counter
#pragma unroll 1
  for (int item = 0; item < 2; ++item) {
    const int qblk = qbs[item];
    const int qw   = qblk*128 + wave*16;        // this wave's 16 q-rows
    const int nst  = qblk*2 + 2;

    // Q fragments (B-operand of S^T = K*Q^T), scale*log2e folded in
    {
      const float* qp = qg + (size_t)(b*S_LEN + qw + l15)*QSTRIDE
                           + h*DH + quad*8;
#pragma unroll
      for (int c = 0; c < 4; ++c) {
        const float4 a4 = ((const float4*)(qp + c*32))[0];
        const float4 b4 = ((const float4*)(qp + c*32))[1];
        u32x4 w;
        w[0] = pk2(a4.x*SCALE_L2, a4.y*SCALE_L2);
        w[1] = pk2(a4.z*SCALE_L2, a4.w*SCALE_L2);
        w[2] = pk2(b4.x*SCALE_L2, b4.y*SCALE_L2);
        w[3] = pk2(b4.z*SCALE_L2, b4.w*SCALE_L2);
        qf[c] = w;
      }
    }
#pragma unroll
    for (int nd = 0; nd < 8; ++nd) oacc[nd] = (f32x4){0.f, 0.f, 0.f, 0.f};
    m_run = -3e38f; l_run = 0.f;

#pragma unroll 1
    for (int i = 0; i < nst; ++i, ++gs) {
      const int k0  = i*KTILE;
      const int buf = gs & 1;
      store_tile(buf);                         // waits vmcnt on prefetch regs
      __syncthreads();                         // tile `gs` visible in buf
      // prefetch next step's tile into registers (overlaps compute below)
      const bool more  = (i + 1 < nst);
      const bool cross = (!more) && (item == 0);
      if (more)       load_regs(i + 1);
      else if (cross) load_regs(0);

      if (k0 <= qw + 15) {                     // wave-uniform causal skip
        const bf16* kb = smem + buf*TILE_ELEMS;

        // ---- S^T = K_tile * Q^T : 4 key-subtiles ----
        f32x4 sacc[4];
#pragma unroll
        for (int mt = 0; mt < 4; ++mt) sacc[mt] = (f32x4){0.f, 0.f, 0.f, 0.f};
#pragma unroll
        for (int c = 0; c < 4; ++c) {
#pragma unroll
          for (int mt = 0; mt < 4; ++mt) {
            const u32x4 af = *(const u32x4*)(kb + koff(c*4 + quad, mt*16 + l15));
            sacc[mt] = __builtin_amdgcn_mfma_f32_16x16x32_bf16(
                __builtin_bit_cast(s16x8, af), __builtin_bit_cast(s16x8, qf[c]),
                sacc[mt], 0, 0, 0);
          }
        }

        // ---- online softmax in exp2 space (per-lane state: q = qw + l15) --
        const bool needmask = (k0 + KTILE - 1 > qw);   // wave-uniform
        const int  qgl = qw + l15;
        float tmax = -3e38f;
#pragma unroll
        for (int mt = 0; mt < 4; ++mt)
#pragma unroll
          for (int r = 0; r < 4; ++r) {
            float sv = sacc[mt][r];
            if (needmask) {
              const int key = k0 + mt*16 + quad*4 + r;
              sv = (key <= qgl) ? sv : -3e38f;
            }
            sacc[mt][r] = sv;
            tmax = fmaxf(tmax, sv);
          }
        tmax = fmaxf(tmax, __shfl_xor(tmax, 16));
        tmax = fmaxf(tmax, __shfl_xor(tmax, 32));
        const float mnew  = fmaxf(m_run, tmax);
        const float alpha = __builtin_amdgcn_exp2f(m_run - mnew);
        m_run = mnew;
        float rsum = 0.f;
#pragma unroll
        for (int mt = 0; mt < 4; ++mt)
#pragma unroll
          for (int r = 0; r < 4; ++r) {
            const float e = __builtin_amdgcn_exp2f(sacc[mt][r] - mnew);
            sacc[mt][r] = e;
            rsum += e;
          }
        rsum += __shfl_xor(rsum, 16);
        rsum += __shfl_xor(rsum, 32);
        l_run = l_run*alpha + rsum;

        s16x4 pa[4];
#pragma unroll
        for (int mt = 0; mt < 4; ++mt) {       // P already in A-layout
          union { bf16 hh[4]; s16x4 s; } u;
#pragma unroll
          for (int r = 0; r < 4; ++r) u.hh[r] = (bf16)sacc[mt][r];
          pa[mt] = u.s;
        }

        // ---- rescale O rows (row = quad*4 + r) ----
#pragma unroll
        for (int r = 0; r < 4; ++r) {
          const float a = __shfl(alpha, (lane & 48) | (quad*4 + r));
#pragma unroll
          for (int nd = 0; nd < 8; ++nd) oacc[nd][r] *= a;
        }

        // ---- O += P * V ----
#pragma unroll
        for (int kt = 0; kt < 4; ++kt)
#pragma unroll
          for (int nd = 0; nd < 8; ++nd) {
            const s16x4 bv = *(const s16x4*)(kb + voff(kt*4 + quad, nd*16 + l15));
            oacc[nd] = __builtin_amdgcn_mfma_f32_16x16x16bf16_1k(
                pa[kt], bv, oacc[nd], 0, 0, 0);
          }
      }
    }

    // ---- epilogue: O / l, fp32 store ----
#pragma unroll
    for (int r = 0; r < 4; ++r) {
      const float li  = __shfl(l_run, (lane & 48) | (quad*4 + r));
      const float inv = 1.0f / li;
      const size_t base = (size_t)(b*S_LEN + qw + quad*4 + r)*QSTRIDE
                        + h*DH + l15;
#pragma unroll
      for (int nd = 0; nd < 8; ++nd)
        og[base + nd*16] = oacc[nd][r] * inv;
    }
  }
}

extern "C" void kernel_launch(void* const* d_in, const int* in_sizes, int n_in,
                              void* d_out, int out_size, void* d_ws, size_t ws_size,
                              hipStream_t stream) {
  const float* q = (const float*)d_in[0];
  const float* k = (const float*)d_in[1];
  const float* v = (const float*)d_in[2];
  float* out = (float*)d_out;
  (void)d_ws; (void)ws_size;
  dim3 grid(8, HQ, 2);       // 8 balanced pairs x 32 heads x 2 batches
  dim3 block(512);
  attn_fwd<<<grid, block, 0, stream>>>(q, k, v, out);
}

// Round 3
// 272.064 us; speedup vs baseline: 2.2784x; 2.2784x over previous
//
#include <hip/hip_runtime.h>
#include <stdint.h>
#include <stddef.h>

// Causal GQA prefill attention, MI355X gfx950.
// Round 6: round-4 structure (218us) with PADDED LDS strides (1024B -> 1040B)
// to fix staging-write bank conflicts. Round-5's XOR swizzle fixed conflicts
// but blew up FETCH_SIZE 190MB->1.03GB (cross-block L2 reuse of K/V collapsed;
// kernel became fabric-BW-bound at 2.2TB/s). This version keeps thread roles,
// global access stream, and base+immediate LDS addressing bitwise identical to
// round 4 -- only the stride constants change.
//
// Bank math (32 banks x 4B):
//   K writes (b128, qwave = 2 keys x 8 chunks): start bank 4*chunk mod 32,
//     +4 per key -> every bank exactly 2x -> free (m136: 2-way = 1.02x).
//   V writes (2 x b128, qwave = 16 units): banks {4u..4u+3}, u vs u+8 -> 2-way.
//   All reads: contiguous 128/256B per quarter-wave -> <=2-way (unchanged).
//
// Verified math pipeline (rounds 0-5): S^T = K*Q^T via mfma_16x16x32_bf16;
// its C-layout (row=key=quad*4+r, col=q=l15) equals the A-operand layout of
// mfma_16x16x16bf16_1k, so softmaxed P feeds PV straight from registers.
//
// LDS tile image (66,560 B for both buffers; strides in bf16 elems):
//   K-part: chunk c in 0..15 at c*520, key r at r*8:  K[r][c*8..c*8+7]
//   V-part: base 8320; unit u in 0..15 at u*520, d at d*4: V[u*4..u*4+3][d]

#define S_LEN   2048
#define HQ      32
#define HKV     8
#define DH      128
#define QSTRIDE (HQ*DH)
#define KSTRIDE (HKV*DH)
// (1/sqrt(128)) * log2(e): softmax in exp2 space
#define SCALE_L2 0.12751139830213113f

#define KTILE      64
#define NTILES     (S_LEN/KTILE)          // 32
#define CSTRIDE    520                    // padded chunk/unit stride (elems)
#define KPART      (16*CSTRIDE)           // 8320 elems
#define TILE_ELEMS (KPART + 16*CSTRIDE)   // 16640 elems (33,280 B)

typedef __bf16 bf16;
typedef short        s16x4 __attribute__((ext_vector_type(4)));
typedef short        s16x8 __attribute__((ext_vector_type(8)));
typedef float        f32x4 __attribute__((ext_vector_type(4)));
typedef unsigned int u32x2 __attribute__((ext_vector_type(2)));
typedef unsigned int u32x4 __attribute__((ext_vector_type(4)));

__device__ __forceinline__ unsigned int pk2(float a, float b) {
  union { bf16 h[2]; unsigned int u; } x;
  x.h[0] = (bf16)a; x.h[1] = (bf16)b;    // fptrunc = RNE
  return x.u;
}

// elem offsets inside the tile image (padded strides, base + immediate form)
__device__ __forceinline__ int koff(int chunk, int key) {
  return chunk*CSTRIDE + key*8;
}
__device__ __forceinline__ int voff(int unit, int d) {
  return KPART + unit*CSTRIDE + d*4;
}

__global__ __launch_bounds__(512, 4)
void attn_fwd(const float* __restrict__ qg, const float* __restrict__ kg,
              const float* __restrict__ vg, float* __restrict__ og) {
  __shared__ bf16 smem[2*TILE_ELEMS];    // 66,560 B, double-buffered

  const int tid   = threadIdx.x;
  const int lane  = tid & 63;
  const int wave  = tid >> 6;            // 8 waves/block
  const int l15   = lane & 15;
  const int quad  = lane >> 4;
  const int pairp = blockIdx.x;          // 0..7
  const int h     = blockIdx.y;          // 0..31
  const int b     = blockIdx.z;          // 0..1
  const int hkv   = h >> 2;

  // staging roles: 512 threads cover the 64x128 K tile and 64x128 V tile
  const int fk_key = tid >> 3, fk_cg = tid & 7;      // K: 2 chunks / thread
  const int fv_u   = tid & 15, fv_dq = tid >> 4;     // V: unit, d-quad
  float4 fkx[4], fvx[4];

  auto load_regs = [&](int t) {
    const float* kp = kg + (size_t)(b*S_LEN + t*KTILE + fk_key)*KSTRIDE
                         + hkv*DH + fk_cg*16;
#pragma unroll
    for (int i = 0; i < 4; ++i) fkx[i] = ((const float4*)kp)[i];
    const int d0 = fv_dq*4;
#pragma unroll
    for (int j = 0; j < 4; ++j)
      fvx[j] = *(const float4*)(vg + (size_t)(b*S_LEN + t*KTILE + fv_u*4 + j)*KSTRIDE
                                   + hkv*DH + d0);
  };
  auto store_tile = [&](int bi) {
    bf16* kb = smem + bi*TILE_ELEMS;
#pragma unroll
    for (int ii = 0; ii < 2; ++ii) {
      u32x4 w;
      w[0] = pk2(fkx[2*ii].x,   fkx[2*ii].y);   w[1] = pk2(fkx[2*ii].z,   fkx[2*ii].w);
      w[2] = pk2(fkx[2*ii+1].x, fkx[2*ii+1].y); w[3] = pk2(fkx[2*ii+1].z, fkx[2*ii+1].w);
      *(u32x4*)(kb + koff(fk_cg*2 + ii, fk_key)) = w;
    }
    const float* g0 = (const float*)&fvx[0];
    const float* g1 = (const float*)&fvx[1];
    const float* g2 = (const float*)&fvx[2];
    const float* g3 = (const float*)&fvx[3];
    // two b128 writes (d pairs {0,1} and {2,3}); 16B-aligned via 1040B strides
#pragma unroll
    for (int i = 0; i < 4; i += 2) {
      u32x4 w;
      w[0] = pk2(g0[i],   g1[i]);
      w[1] = pk2(g2[i],   g3[i]);
      w[2] = pk2(g0[i+1], g1[i+1]);
      w[3] = pk2(g2[i+1], g3[i+1]);
      *(u32x4*)(kb + voff(fv_u, fv_dq*4 + i)) = w;
    }
  };

  f32x4 oacc[8];
  float m_run, l_run;
  u32x4 qf[4];

  const int qbs[2] = { pairp, 15 - pairp };     // balanced: 34 steps total
  load_regs(0);

  int gs = 0;                                   // flat step counter
#pragma unroll 1
  for (int item = 0; item < 2; ++item) {
    const int qblk = qbs[item];
    const int qw   = qblk*128 + wave*16;        // this wave's 16 q-rows
    const int nst  = qblk*2 + 2;

    // Q fragments (B-operand of S^T = K*Q^T), scale*log2e folded in
    {
      const float* qp = qg + (size_t)(b*S_LEN + qw + l15)*QSTRIDE
                           + h*DH + quad*8;
#pragma unroll
      for (int c = 0; c < 4; ++c) {
        const float4 a4 = ((const float4*)(qp + c*32))[0];
        const float4 b4 = ((const float4*)(qp + c*32))[1];
        u32x4 w;
        w[0] = pk2(a4.x*SCALE_L2, a4.y*SCALE_L2);
        w[1] = pk2(a4.z*SCALE_L2, a4.w*SCALE_L2);
        w[2] = pk2(b4.x*SCALE_L2, b4.y*SCALE_L2);
        w[3] = pk2(b4.z*SCALE_L2, b4.w*SCALE_L2);
        qf[c] = w;
      }
    }
#pragma unroll
    for (int nd = 0; nd < 8; ++nd) oacc[nd] = (f32x4){0.f, 0.f, 0.f, 0.f};
    m_run = -3e38f; l_run = 0.f;

#pragma unroll 1
    for (int i = 0; i < nst; ++i, ++gs) {
      const int k0  = i*KTILE;
      const int buf = gs & 1;
      store_tile(buf);                         // waits vmcnt on prefetch regs
      __syncthreads();                         // tile `gs` visible in buf
      // prefetch next step's tile into registers (overlaps compute below)
      const bool more  = (i + 1 < nst);
      const bool cross = (!more) && (item == 0);
      if (more)       load_regs(i + 1);
      else if (cross) load_regs(0);

      if (k0 <= qw + 15) {                     // wave-uniform causal skip
        const bf16* kb = smem + buf*TILE_ELEMS;

        // ---- S^T = K_tile * Q^T : 4 key-subtiles ----
        f32x4 sacc[4];
#pragma unroll
        for (int mt = 0; mt < 4; ++mt) sacc[mt] = (f32x4){0.f, 0.f, 0.f, 0.f};
#pragma unroll
        for (int c = 0; c < 4; ++c) {
#pragma unroll
          for (int mt = 0; mt < 4; ++mt) {
            const u32x4 af = *(const u32x4*)(kb + koff(c*4 + quad, mt*16 + l15));
            sacc[mt] = __builtin_amdgcn_mfma_f32_16x16x32_bf16(
                __builtin_bit_cast(s16x8, af), __builtin_bit_cast(s16x8, qf[c]),
                sacc[mt], 0, 0, 0);
          }
        }

        // ---- online softmax in exp2 space (per-lane state: q = qw + l15) --
        const bool needmask = (k0 + KTILE - 1 > qw);   // wave-uniform
        const int  qgl = qw + l15;
        float tmax = -3e38f;
#pragma unroll
        for (int mt = 0; mt < 4; ++mt)
#pragma unroll
          for (int r = 0; r < 4; ++r) {
            float sv = sacc[mt][r];
            if (needmask) {
              const int key = k0 + mt*16 + quad*4 + r;
              sv = (key <= qgl) ? sv : -3e38f;
            }
            sacc[mt][r] = sv;
            tmax = fmaxf(tmax, sv);
          }
        tmax = fmaxf(tmax, __shfl_xor(tmax, 16));
        tmax = fmaxf(tmax, __shfl_xor(tmax, 32));
        const float mnew  = fmaxf(m_run, tmax);
        const float alpha = __builtin_amdgcn_exp2f(m_run - mnew);
        m_run = mnew;
        float rsum = 0.f;
#pragma unroll
        for (int mt = 0; mt < 4; ++mt)
#pragma unroll
          for (int r = 0; r < 4; ++r) {
            const float e = __builtin_amdgcn_exp2f(sacc[mt][r] - mnew);
            sacc[mt][r] = e;
            rsum += e;
          }
        rsum += __shfl_xor(rsum, 16);
        rsum += __shfl_xor(rsum, 32);
        l_run = l_run*alpha + rsum;

        s16x4 pa[4];
#pragma unroll
        for (int mt = 0; mt < 4; ++mt) {       // P already in A-layout
          union { bf16 hh[4]; s16x4 s; } u;
#pragma unroll
          for (int r = 0; r < 4; ++r) u.hh[r] = (bf16)sacc[mt][r];
          pa[mt] = u.s;
        }

        // ---- rescale O rows (row = quad*4 + r) ----
#pragma unroll
        for (int r = 0; r < 4; ++r) {
          const float a = __shfl(alpha, (lane & 48) | (quad*4 + r));
#pragma unroll
          for (int nd = 0; nd < 8; ++nd) oacc[nd][r] *= a;
        }

        // ---- O += P * V ----
#pragma unroll
        for (int kt = 0; kt < 4; ++kt)
#pragma unroll
          for (int nd = 0; nd < 8; ++nd) {
            const s16x4 bv = *(const s16x4*)(kb + voff(kt*4 + quad, nd*16 + l15));
            oacc[nd] = __builtin_amdgcn_mfma_f32_16x16x16bf16_1k(
                pa[kt], bv, oacc[nd], 0, 0, 0);
          }
      }
    }

    // ---- epilogue: O / l, fp32 store ----
#pragma unroll
    for (int r = 0; r < 4; ++r) {
      const float li  = __shfl(l_run, (lane & 48) | (quad*4 + r));
      const float inv = 1.0f / li;
      const size_t base = (size_t)(b*S_LEN + qw + quad*4 + r)*QSTRIDE
                        + h*DH + l15;
#pragma unroll
      for (int nd = 0; nd < 8; ++nd)
        og[base + nd*16] = oacc[nd][r] * inv;
    }
  }
}

extern "C" void kernel_launch(void* const* d_in, const int* in_sizes, int n_in,
                              void* d_out, int out_size, void* d_ws, size_t ws_size,
                              hipStream_t stream) {
  const float* q = (const float*)d_in[0];
  const float* k = (const float*)d_in[1];
  const float* v = (const float*)d_in[2];
  float* out = (float*)d_out;
  (void)d_ws; (void)ws_size;
  dim3 grid(8, HQ, 2);       // 8 balanced pairs x 32 heads x 2 batches
  dim3 block(512);
  attn_fwd<<<grid, block, 0, stream>>>(q, k, v, out);
}

// Round 4
// 257.487 us; speedup vs baseline: 2.4074x; 1.0566x over previous
//
#include <hip/hip_runtime.h>
#include <stdint.h>
#include <stddef.h>

// Causal GQA prefill attention, MI355X gfx950.
// Round 7: chain-shortening on the round-6 structure (184.6us). Profile said
// per-SIMD issue util ~15-20% -> latency-bound lockstep schedule; occupancy is
// register-capped (112 regs -> 16 waves/CU), so we shorten the per-step serial
// chain instead of adding waves:
//   1. T13 defer-max: skip alpha/rescale/broadcasts when __all(tmax<=m+8).
//   2. Depth-4 tree reductions for tile max and row sum (were 16-deep chains).
//   3. Prefetch global loads issued BEFORE the barrier (extra latency hiding).
//
// Round-6 invariants kept: padded LDS strides (1040B) -> staging writes <=2-way
// bank conflicts; global access stream unchanged (L2-friendly); verified math:
// S^T = K*Q^T via mfma_16x16x32_bf16, C-layout = A-layout of 16x16x16bf16_1k,
// so softmaxed P feeds PV straight from registers.
//
// LDS tile image (66,560 B both buffers; strides in bf16 elems):
//   K-part: chunk c in 0..15 at c*520, key r at r*8:  K[r][c*8..c*8+7]
//   V-part: base 8320; unit u in 0..15 at u*520, d at d*4: V[u*4..u*4+3][d]

#define S_LEN   2048
#define HQ      32
#define HKV     8
#define DH      128
#define QSTRIDE (HQ*DH)
#define KSTRIDE (HKV*DH)
// (1/sqrt(128)) * log2(e): softmax in exp2 space
#define SCALE_L2 0.12751139830213113f
// defer-max threshold (exp2 units): P bounded by 2^8, bf16 rel-err unchanged
#define DEFER_THR 8.0f

#define KTILE      64
#define NTILES     (S_LEN/KTILE)          // 32
#define CSTRIDE    520                    // padded chunk/unit stride (elems)
#define KPART      (16*CSTRIDE)           // 8320 elems
#define TILE_ELEMS (KPART + 16*CSTRIDE)   // 16640 elems (33,280 B)

typedef __bf16 bf16;
typedef short        s16x4 __attribute__((ext_vector_type(4)));
typedef short        s16x8 __attribute__((ext_vector_type(8)));
typedef float        f32x4 __attribute__((ext_vector_type(4)));
typedef unsigned int u32x2 __attribute__((ext_vector_type(2)));
typedef unsigned int u32x4 __attribute__((ext_vector_type(4)));

__device__ __forceinline__ unsigned int pk2(float a, float b) {
  union { bf16 h[2]; unsigned int u; } x;
  x.h[0] = (bf16)a; x.h[1] = (bf16)b;    // fptrunc = RNE
  return x.u;
}

// elem offsets inside the tile image (padded strides, base + immediate form)
__device__ __forceinline__ int koff(int chunk, int key) {
  return chunk*CSTRIDE + key*8;
}
__device__ __forceinline__ int voff(int unit, int d) {
  return KPART + unit*CSTRIDE + d*4;
}

__global__ __launch_bounds__(512, 4)
void attn_fwd(const float* __restrict__ qg, const float* __restrict__ kg,
              const float* __restrict__ vg, float* __restrict__ og) {
  __shared__ bf16 smem[2*TILE_ELEMS];    // 66,560 B, double-buffered

  const int tid   = threadIdx.x;
  const int lane  = tid & 63;
  const int wave  = tid >> 6;            // 8 waves/block
  const int l15   = lane & 15;
  const int quad  = lane >> 4;
  const int pairp = blockIdx.x;          // 0..7
  const int h     = blockIdx.y;          // 0..31
  const int b     = blockIdx.z;          // 0..1
  const int hkv   = h >> 2;

  // staging roles: 512 threads cover the 64x128 K tile and 64x128 V tile
  const int fk_key = tid >> 3, fk_cg = tid & 7;      // K: 2 chunks / thread
  const int fv_u   = tid & 15, fv_dq = tid >> 4;     // V: unit, d-quad
  float4 fkx[4], fvx[4];

  auto load_regs = [&](int t) {
    const float* kp = kg + (size_t)(b*S_LEN + t*KTILE + fk_key)*KSTRIDE
                         + hkv*DH + fk_cg*16;
#pragma unroll
    for (int i = 0; i < 4; ++i) fkx[i] = ((const float4*)kp)[i];
    const int d0 = fv_dq*4;
#pragma unroll
    for (int j = 0; j < 4; ++j)
      fvx[j] = *(const float4*)(vg + (size_t)(b*S_LEN + t*KTILE + fv_u*4 + j)*KSTRIDE
                                   + hkv*DH + d0);
  };
  auto store_tile = [&](int bi) {
    bf16* kb = smem + bi*TILE_ELEMS;
#pragma unroll
    for (int ii = 0; ii < 2; ++ii) {
      u32x4 w;
      w[0] = pk2(fkx[2*ii].x,   fkx[2*ii].y);   w[1] = pk2(fkx[2*ii].z,   fkx[2*ii].w);
      w[2] = pk2(fkx[2*ii+1].x, fkx[2*ii+1].y); w[3] = pk2(fkx[2*ii+1].z, fkx[2*ii+1].w);
      *(u32x4*)(kb + koff(fk_cg*2 + ii, fk_key)) = w;
    }
    const float* g0 = (const float*)&fvx[0];
    const float* g1 = (const float*)&fvx[1];
    const float* g2 = (const float*)&fvx[2];
    const float* g3 = (const float*)&fvx[3];
    // two b128 writes (d pairs {0,1} and {2,3}); 16B-aligned via 1040B strides
#pragma unroll
    for (int i = 0; i < 4; i += 2) {
      u32x4 w;
      w[0] = pk2(g0[i],   g1[i]);
      w[1] = pk2(g2[i],   g3[i]);
      w[2] = pk2(g0[i+1], g1[i+1]);
      w[3] = pk2(g2[i+1], g3[i+1]);
      *(u32x4*)(kb + voff(fv_u, fv_dq*4 + i)) = w;
    }
  };

  f32x4 oacc[8];
  float m_run, l_run;
  u32x4 qf[4];

  const int qbs[2] = { pairp, 15 - pairp };     // balanced: 34 steps total
  load_regs(0);

  int gs = 0;                                   // flat step counter
#pragma unroll 1
  for (int item = 0; item < 2; ++item) {
    const int qblk = qbs[item];
    const int qw   = qblk*128 + wave*16;        // this wave's 16 q-rows
    const int nst  = qblk*2 + 2;

    // Q fragments (B-operand of S^T = K*Q^T), scale*log2e folded in
    {
      const float* qp = qg + (size_t)(b*S_LEN + qw + l15)*QSTRIDE
                           + h*DH + quad*8;
#pragma unroll
      for (int c = 0; c < 4; ++c) {
        const float4 a4 = ((const float4*)(qp + c*32))[0];
        const float4 b4 = ((const float4*)(qp + c*32))[1];
        u32x4 w;
        w[0] = pk2(a4.x*SCALE_L2, a4.y*SCALE_L2);
        w[1] = pk2(a4.z*SCALE_L2, a4.w*SCALE_L2);
        w[2] = pk2(b4.x*SCALE_L2, b4.y*SCALE_L2);
        w[3] = pk2(b4.z*SCALE_L2, b4.w*SCALE_L2);
        qf[c] = w;
      }
    }
#pragma unroll
    for (int nd = 0; nd < 8; ++nd) oacc[nd] = (f32x4){0.f, 0.f, 0.f, 0.f};
    m_run = -3e38f; l_run = 0.f;

#pragma unroll 1
    for (int i = 0; i < nst; ++i, ++gs) {
      const int k0  = i*KTILE;
      const int buf = gs & 1;
      store_tile(buf);                         // waits vmcnt on prefetch regs
      // issue next step's global loads BEFORE the barrier (R7: more latency
      // hiding; only WAR on fkx/fvx which store_tile just consumed)
      const bool more  = (i + 1 < nst);
      const bool cross = (!more) && (item == 0);
      if (more)       load_regs(i + 1);
      else if (cross) load_regs(0);
      __syncthreads();                         // tile `gs` visible in buf

      if (k0 <= qw + 15) {                     // wave-uniform causal skip
        const bf16* kb = smem + buf*TILE_ELEMS;

        // ---- S^T = K_tile * Q^T : 4 key-subtiles ----
        f32x4 sacc[4];
#pragma unroll
        for (int mt = 0; mt < 4; ++mt) sacc[mt] = (f32x4){0.f, 0.f, 0.f, 0.f};
#pragma unroll
        for (int c = 0; c < 4; ++c) {
#pragma unroll
          for (int mt = 0; mt < 4; ++mt) {
            const u32x4 af = *(const u32x4*)(kb + koff(c*4 + quad, mt*16 + l15));
            sacc[mt] = __builtin_amdgcn_mfma_f32_16x16x32_bf16(
                __builtin_bit_cast(s16x8, af), __builtin_bit_cast(s16x8, qf[c]),
                sacc[mt], 0, 0, 0);
          }
        }

        // ---- online softmax in exp2 space (per-lane state: q = qw + l15) --
        const bool needmask = (k0 + KTILE - 1 > qw);   // wave-uniform
        const int  qgl = qw + l15;
        if (needmask) {
#pragma unroll
          for (int mt = 0; mt < 4; ++mt)
#pragma unroll
            for (int r = 0; r < 4; ++r) {
              const int key = k0 + mt*16 + quad*4 + r;
              if (key > qgl) sacc[mt][r] = -3e38f;
            }
        }
        // depth-4 tree max over the 16 tile scores (R7: was 16-deep chain)
        float tmax;
        {
          float t8[8];
#pragma unroll
          for (int j = 0; j < 8; ++j)
            t8[j] = fmaxf(sacc[j >> 2][j & 3], sacc[(j >> 2) + 2][j & 3]);
          float t4[4];
#pragma unroll
          for (int j = 0; j < 4; ++j) t4[j] = fmaxf(t8[j], t8[j + 4]);
          tmax = fmaxf(fmaxf(t4[0], t4[2]), fmaxf(t4[1], t4[3]));
        }
        tmax = fmaxf(tmax, __shfl_xor(tmax, 16));
        tmax = fmaxf(tmax, __shfl_xor(tmax, 32));

        // T13 defer-max: skip alpha/rescale when max growth is small
        const bool defer = __all(tmax <= m_run + DEFER_THR);
        float alpha = 1.0f;
        if (!defer) {
          const float mnew = fmaxf(m_run, tmax);
          alpha = __builtin_amdgcn_exp2f(m_run - mnew);
          m_run = mnew;
        }
#pragma unroll
        for (int mt = 0; mt < 4; ++mt)
#pragma unroll
          for (int r = 0; r < 4; ++r)
            sacc[mt][r] = __builtin_amdgcn_exp2f(sacc[mt][r] - m_run);
        // depth-4 tree sum (R7: was 15-deep chain)
        float rsum;
        {
          float s8[8];
#pragma unroll
          for (int j = 0; j < 8; ++j)
            s8[j] = sacc[j >> 2][j & 3] + sacc[(j >> 2) + 2][j & 3];
          float s4[4];
#pragma unroll
          for (int j = 0; j < 4; ++j) s4[j] = s8[j] + s8[j + 4];
          rsum = (s4[0] + s4[2]) + (s4[1] + s4[3]);
        }
        rsum += __shfl_xor(rsum, 16);
        rsum += __shfl_xor(rsum, 32);

        if (defer) {
          l_run += rsum;
        } else {
          l_run = l_run*alpha + rsum;
          // ---- rescale O rows (row = quad*4 + r) ----
#pragma unroll
          for (int r = 0; r < 4; ++r) {
            const float a = __shfl(alpha, (lane & 48) | (quad*4 + r));
#pragma unroll
            for (int nd = 0; nd < 8; ++nd) oacc[nd][r] *= a;
          }
        }

        s16x4 pa[4];
#pragma unroll
        for (int mt = 0; mt < 4; ++mt) {       // P already in A-layout
          union { bf16 hh[4]; s16x4 s; } u;
#pragma unroll
          for (int r = 0; r < 4; ++r) u.hh[r] = (bf16)sacc[mt][r];
          pa[mt] = u.s;
        }

        // ---- O += P * V ----
#pragma unroll
        for (int kt = 0; kt < 4; ++kt)
#pragma unroll
          for (int nd = 0; nd < 8; ++nd) {
            const s16x4 bv = *(const s16x4*)(kb + voff(kt*4 + quad, nd*16 + l15));
            oacc[nd] = __builtin_amdgcn_mfma_f32_16x16x16bf16_1k(
                pa[kt], bv, oacc[nd], 0, 0, 0);
          }
      }
    }

    // ---- epilogue: O / l, fp32 store ----
#pragma unroll
    for (int r = 0; r < 4; ++r) {
      const float li  = __shfl(l_run, (lane & 48) | (quad*4 + r));
      const float inv = 1.0f / li;
      const size_t base = (size_t)(b*S_LEN + qw + quad*4 + r)*QSTRIDE
                        + h*DH + l15;
#pragma unroll
      for (int nd = 0; nd < 8; ++nd)
        og[base + nd*16] = oacc[nd][r] * inv;
    }
  }
}

extern "C" void kernel_launch(void* const* d_in, const int* in_sizes, int n_in,
                              void* d_out, int out_size, void* d_ws, size_t ws_size,
                              hipStream_t stream) {
  const float* q = (const float*)d_in[0];
  const float* k = (const float*)d_in[1];
  const float* v = (const float*)d_in[2];
  float* out = (float*)d_out;
  (void)d_ws; (void)ws_size;
  dim3 grid(8, HQ, 2);       // 8 balanced pairs x 32 heads x 2 batches
  dim3 block(512);
  attn_fwd<<<grid, block, 0, stream>>>(q, k, v, out);
}